// Round 2
// baseline (153.862 us; speedup 1.0000x reference)
//
#include <hip/hip_runtime.h>
#include <cmath>

#define EPS 1e-5f
#define SZ 2097152  // N*H*W*E = 4*64*64*128

typedef __attribute__((ext_vector_type(8))) short short8;   // 8 bf16 (4 VGPRs)
typedef __attribute__((ext_vector_type(4))) float floatx4;  // MFMA C/D frag

__device__ __forceinline__ float dot4(float4 a, float4 b) {
  return fmaf(a.x, b.x, fmaf(a.y, b.y, fmaf(a.z, b.z, a.w * b.w)));
}

__device__ __forceinline__ short f2bf(float f) {
  union { float f; unsigned u; } v; v.f = f;
  unsigned r = v.u + 0x7fff + ((v.u >> 16) & 1);  // RNE
  return (short)(r >> 16);
}

#define MFMA16(a, b, c) __builtin_amdgcn_mfma_f32_16x16x32_bf16(a, b, c, 0, 0, 0)

// ---------------------------------------------------------------- K0: prep (weights fp32->bf16 padded; t = bil_w.qcoeff)
// grid 64, block 256
__global__ __launch_bounds__(256) void k_prep(const float* __restrict__ w1,
    const float* __restrict__ w2, const float* __restrict__ wq,
    const float* __restrict__ wk, const float* __restrict__ wv,
    const float* __restrict__ bil_w, const float* __restrict__ qcoeff,
    short* __restrict__ w1bf, short* __restrict__ w2bf,
    short* __restrict__ wqbf, short* __restrict__ wkbf, short* __restrict__ wvbf,
    short* __restrict__ tb) {
  __shared__ float qs[256];
  int tid = threadIdx.x;
  qs[tid] = qcoeff[tid];
  __syncthreads();
  int tid0 = blockIdx.x * 256 + tid;
  int stride = gridDim.x * 256;
  for (int i = tid0; i < 16384; i += stride) {
    int flat = i * 4; int f = flat >> 7, c = flat & 127;
    float4 v = *(const float4*)&w1[flat];
    short t4[4] = {f2bf(v.x), f2bf(v.y), f2bf(v.z), f2bf(v.w)};
    *(uint2*)&w1bf[f * 136 + c] = *(uint2*)t4;
  }
  for (int i = tid0; i < 16384; i += stride) {
    int flat = i * 4; int o = flat >> 9, j = flat & 511;
    int ck = j >> 7, jj = j & 127;
    float4 v = *(const float4*)&w2[flat];
    short t4[4] = {f2bf(v.x), f2bf(v.y), f2bf(v.z), f2bf(v.w)};
    *(uint2*)&w2bf[(ck * 128 + o) * 136 + jj] = *(uint2*)t4;
  }
  for (int i = tid0; i < 4096; i += stride) {
    int flat = i * 4; int o = flat >> 7, c = flat & 127;
    float4 a = *(const float4*)&wq[flat];
    float4 b = *(const float4*)&wk[flat];
    float4 cc = *(const float4*)&wv[flat];
    short ta[4] = {f2bf(a.x), f2bf(a.y), f2bf(a.z), f2bf(a.w)};
    short tb4[4] = {f2bf(b.x), f2bf(b.y), f2bf(b.z), f2bf(b.w)};
    short tc[4] = {f2bf(cc.x), f2bf(cc.y), f2bf(cc.z), f2bf(cc.w)};
    *(uint2*)&wqbf[o * 136 + c] = *(uint2*)ta;
    *(uint2*)&wkbf[o * 136 + c] = *(uint2*)tb4;
    *(uint2*)&wvbf[o * 136 + c] = *(uint2*)tc;
  }
  {
    int flat = tid0;                          // o*128 + i
    const float* wrow = bil_w + (size_t)flat * 64;
    float acc[4] = {0.f, 0.f, 0.f, 0.f};
    for (int qq = 0; qq < 64; qq += 4) {
      float4 w4 = *(const float4*)&wrow[qq];
#pragma unroll
      for (int nn = 0; nn < 4; ++nn) {
        const float* qc = &qs[nn * 64 + qq];
        acc[nn] = fmaf(w4.x, qc[0], fmaf(w4.y, qc[1], fmaf(w4.z, qc[2], fmaf(w4.w, qc[3], acc[nn]))));
      }
    }
    int o = flat >> 7, i = flat & 127;
#pragma unroll
    for (int nn = 0; nn < 4; ++nn) tb[nn * 17408 + o * 136 + i] = f2bf(acc[nn]);
  }
}

// ---------------------------------------------------------------- K1: LN1 + transpose + QKV (LDS-staged weights)
// grid 512 = (n*64+y)*2+half, block 512 = 8 waves; 32 px/block; ~61 KB LDS -> 2 blocks/CU
__global__ __launch_bounds__(512) void k_qkvln(const float* __restrict__ x,
    const float* __restrict__ g, const float* __restrict__ b,
    const short* __restrict__ wqbf, const short* __restrict__ wkbf,
    const short* __restrict__ wvbf, const float* __restrict__ bq,
    const float* __restrict__ bk, const float* __restrict__ bv,
    float* __restrict__ xnhwc, short* __restrict__ qbf,
    short* __restrict__ kbf, short* __restrict__ vtb) {
  __shared__ float tile[128 * 33];               // x NCHW tile [c][xpl]
  __shared__ float mres[32], rres[32];
  __shared__ __align__(16) short xs[32 * 136];   // A: [pxl][c] bf16
  __shared__ __align__(16) short ws[128 * 136];  // B: [o][c] bf16 (staged per matrix)
  int tid = threadIdx.x;
  int bid = blockIdx.x;
  int half = bid & 1, ny = bid >> 1;
  int n = ny >> 6, y = ny & 63;
  const float* xb = x + (size_t)n * 524288 + y * 64 + half * 32;
  for (int it = 0; it < 8; ++it) {
    int flat = it * 512 + tid;                   // c*32 + xpl
    int c = flat >> 5, xpl = flat & 31;
    tile[c * 33 + xpl] = xb[(size_t)c * 4096 + xpl];
  }
  __syncthreads();
  {
    int pxl = tid >> 4, cl = tid & 15;
    float s = 0.f, sq = 0.f;
#pragma unroll
    for (int j = 0; j < 8; ++j) {
      float v = tile[(cl * 8 + j) * 33 + pxl];
      s += v; sq += v * v;
    }
    s += __shfl_xor(s, 1);  sq += __shfl_xor(sq, 1);
    s += __shfl_xor(s, 2);  sq += __shfl_xor(sq, 2);
    s += __shfl_xor(s, 4);  sq += __shfl_xor(sq, 4);
    s += __shfl_xor(s, 8);  sq += __shfl_xor(sq, 8);
    if (cl == 0) {
      float m = s * (1.f / 128.f);
      float var = sq * (1.f / 128.f) - m * m;
      mres[pxl] = m;
      rres[pxl] = rsqrtf(var + EPS);
    }
  }
  __syncthreads();
  size_t rowbase = (size_t)ny * 8192 + half * 4096;
  for (int it = 0; it < 8; ++it) {
    int flat = it * 512 + tid;                   // pxl*128 + c
    int c = flat & 127, pxl = flat >> 7;
    float v = tile[c * 33 + pxl];
    xnhwc[rowbase + flat] = v;
    xs[pxl * 136 + c] = f2bf((v - mres[pxl]) * rres[pxl] * g[c] + b[c]);
  }
  __syncthreads();
  int w = tid >> 6, lane = tid & 63;
  int quad = lane >> 4, r16 = lane & 15;
  int wm = w & 1, wn = w >> 1;                   // wn in [0,4)
  int stripl = wm * 16;
  short8 a[4];
#pragma unroll
  for (int kk = 0; kk < 4; ++kk)
    a[kk] = *(const short8*)&xs[(stripl + r16) * 136 + kk * 32 + quad * 8];
  const short* wptr[3] = {wqbf, wkbf, wvbf};
  const float* bptr[3] = {bq, bk, bv};
  for (int m = 0; m < 3; ++m) {
    __syncthreads();   // previous matrix's ws readers done
    const short* wp = wptr[m];
    for (int i = tid; i < 2176; i += 512)
      *(short8*)&ws[i * 8] = *(const short8*)&wp[i * 8];
    __syncthreads();
    const float* bb = bptr[m];
#pragma unroll
    for (int nt = 0; nt < 2; ++nt) {
      int o0 = wn * 32 + nt * 16;
      floatx4 acc = {0.f, 0.f, 0.f, 0.f};
#pragma unroll
      for (int kk = 0; kk < 4; ++kk) {
        short8 bfr = *(const short8*)&ws[(o0 + r16) * 136 + kk * 32 + quad * 8];
        acc = MFMA16(a[kk], bfr, acc);
      }
      float bv2 = bb[o0 + r16];
      if (m < 2) {
        short* dst = (m == 0) ? qbf : kbf;
#pragma unroll
        for (int r = 0; r < 4; ++r) {
          int pxl = stripl + quad * 4 + r;
          dst[rowbase + pxl * 128 + o0 + r16] = f2bf(acc[r] + bv2);
        }
      } else {
        short t4[4] = {f2bf(acc[0] + bv2), f2bf(acc[1] + bv2),
                       f2bf(acc[2] + bv2), f2bf(acc[3] + bv2)};
        *(uint2*)&vtb[(size_t)(n * 128 + o0 + r16) * 4096 + y * 64 + half * 32 +
                      stripl + quad * 4] = *(uint2*)t4;
      }
    }
  }
}

// ---------------------------------------------------------------- K2: attention + bilinear + LN2 + FFN + NCHW out
// v2: 512 blocks x 512 threads (half-row / 32 px per block), direct-global
// B-operands for bilinear/FFN weights (L2-hot, no LDS staging), LDS 70272 B -> 2 blocks/CU.
// grid 512 = (n*64+y)*2+half, block 512 = 8 waves
__global__ __launch_bounds__(512, 4) void k_at(const short* __restrict__ qbf,
    const short* __restrict__ kbf, const short* __restrict__ vtb,
    const float* __restrict__ rel_bias, const short* __restrict__ tb,
    const float* __restrict__ bil_b, const float* __restrict__ xnhwc,
    const float* __restrict__ g2, const float* __restrict__ b2ln,
    const short* __restrict__ w1bf, const float* __restrict__ b1,
    const short* __restrict__ w2bf, const float* __restrict__ b2,
    float* __restrict__ out) {
  // layout: [0,25600) ssfw (8 waves * 16*50 f32); [25600,43008) Abw (8 * 16*68 bf16);
  // [43008,44672) bias (8 * 52 f32); h1s overlays [0,8704) in FFN phase;
  // [44672,53376) z3s [32][136] bf16; [53376,70272) z2s [32][132] f32
  __shared__ __align__(16) char smem[70272];
  short* h1s = (short*)smem;                    // FFN phase only (attn region dead then)
  short* z3s = (short*)(smem + 44672);
  float* z2s = (float*)(smem + 53376);
  int tid = threadIdx.x;
  int bid = blockIdx.x;
  int half = bid & 1, ny = bid >> 1;
  int n = ny >> 6, y = ny & 63;
  int w16 = tid >> 6, lane = tid & 63;
  int quad = lane >> 4, r16 = lane & 15;
  size_t rowbase = (size_t)ny * 8192;
  int wm = w16 & 1, wn = w16 >> 1;              // tail-phase wave tiling
  int stripL = wm * 16;                         // local px strip [0,32)
  // prefetch bilinear residual (x_nhwc) into registers at kernel entry
  float xres[2][4];
#pragma unroll
  for (int nt = 0; nt < 2; ++nt)
#pragma unroll
    for (int r = 0; r < 4; ++r)
      xres[nt][r] = xnhwc[rowbase + (half * 32 + stripL + quad * 4 + r) * 128 +
                          wn * 32 + nt * 16 + r16];
  // ---------- attention phase: wave = (h, local strip) ----------
  {
    int h = w16 >> 1, swl = w16 & 1;
    int sg = half * 2 + swl;                    // global strip idx [0,4)
    int strip = sg * 16;                        // global px strip
    float* ssfw = (float*)(smem + w16 * 3200);
    short* Abw = (short*)(smem + 25600 + w16 * 2176);
    float* biasw = (float*)(smem + 43008 + w16 * 208);
    {
      unsigned* ad = (unsigned*)Abw;
      for (int i = lane; i < 544; i += 64) ad[i] = 0u;
    }
    if (lane < 49) biasw[lane] = rel_bias[h * 49 + lane];
    const short* qrow = qbf + (size_t)n * 524288 + (size_t)y * 8192 + h * 32;
    short8 qf = *(const short8*)&qrow[(strip + r16) * 128 + quad * 8];
    const short* kbp = kbf + (size_t)n * 524288 + h * 32;
#pragma unroll
    for (int r = 0; r < 7; ++r) {
      int yy = y + r - 3;
      bool yok = (unsigned)yy < 64u;
      int yyc = min(max(yy, 0), 63);
#pragma unroll
      for (int t = 0; t < 2; ++t) {
        int xxc = (sg + t) * 16 + r16;
        int gx = xxc - 3;
        bool ok = yok && ((unsigned)gx < 64u);
        int gxc = min(max(gx, 0), 63);
        short8 bf = *(const short8*)&kbp[(size_t)(yyc * 64 + gxc) * 128 + quad * 8];
        floatx4 c = MFMA16(qf, bf, ((floatx4){0.f, 0.f, 0.f, 0.f}));
#pragma unroll
        for (int rr = 0; rr < 4; ++rr) {
          int lrow = quad * 4 + rr;
          int dx = xxc - (strip + lrow);
          if ((unsigned)dx < 7u) {
            float val = ok ? c[rr] : 0.f;       // reference zero-pads K
            ssfw[lrow * 50 + r * 7 + dx] = val + biasw[r * 7 + dx];
          }
        }
      }
    }
    {
      int lrow = lane >> 2, sub = lane & 3;
      int p0 = sub * 12;
      float sv[13];
      float mx = -1e30f;
#pragma unroll
      for (int pi = 0; pi < 13; ++pi) {         // p0+pi <= 48: always in-row
        sv[pi] = ssfw[lrow * 50 + p0 + pi];
        mx = fmaxf(mx, sv[pi]);
      }
      mx = fmaxf(mx, __shfl_xor(mx, 1));
      mx = fmaxf(mx, __shfl_xor(mx, 2));
      float sum = 0.f;
#pragma unroll
      for (int pi = 0; pi < 13; ++pi) {
        float e = __expf(sv[pi] - mx);
        if (pi == 12 && sub != 3) e = 0.f;      // slot belongs to next sub
        sv[pi] = e; sum += e;
      }
      sum += __shfl_xor(sum, 1);
      sum += __shfl_xor(sum, 2);
      float inv = 1.f / sum;
#pragma unroll
      for (int pi = 0; pi < 13; ++pi)
        if (pi < 12 || sub == 3) ssfw[lrow * 50 + p0 + pi] = sv[pi] * inv;
    }
    floatx4 oacc[2] = {(floatx4){0.f, 0.f, 0.f, 0.f}, (floatx4){0.f, 0.f, 0.f, 0.f}};
    int kk0 = (sg == 3) ? 1 : 0;
    int kk1 = (sg == 0) ? 0 : 1;
    int lrow = lane >> 2, sub = lane & 3;
    int pxg = strip + lrow;
    const short* vbp = vtb + (size_t)(n * 128 + h * 32) * 4096;
    for (int r = 0; r < 7; ++r) {
      int yy = y + r - 3;
      bool yok = (unsigned)yy < 64u;
      int yyc = min(max(yy, 0), 63);
      int c0 = pxg + sub - 3;
      if ((unsigned)c0 < 64u) Abw[lrow * 68 + c0] = f2bf(ssfw[lrow * 50 + r * 7 + sub]);
      int c1 = pxg + sub + 1;
      if (sub < 3 && (unsigned)c1 < 64u)
        Abw[lrow * 68 + c1] = f2bf(ssfw[lrow * 50 + r * 7 + sub + 4]);
      for (int kk = kk0; kk <= kk1; ++kk) {
        short8 af = *(const short8*)&Abw[r16 * 68 + kk * 32 + quad * 8];
#pragma unroll
        for (int nt = 0; nt < 2; ++nt) {
          short8 vf = *(const short8*)&vbp[(size_t)(nt * 16 + r16) * 4096 + yyc * 64 + kk * 32 + quad * 8];
          if (!yok) vf = (short8){0, 0, 0, 0, 0, 0, 0, 0};  // reference zero-pads V
          oacc[nt] = MFMA16(af, vf, oacc[nt]);
        }
      }
    }
#pragma unroll
    for (int nt = 0; nt < 2; ++nt)
#pragma unroll
      for (int rr = 0; rr < 4; ++rr) {
        int pxl = swl * 16 + quad * 4 + rr;     // local px within this block's 32
        z3s[pxl * 136 + h * 32 + nt * 16 + r16] = f2bf(oacc[nt][rr]);
      }
  }
  __syncthreads();
  // ---------- bilinear (B = t, direct from global; L2-hot) ----------
  {
    const short* tn = tb + (size_t)n * 17408;
    short8 a[4];
#pragma unroll
    for (int kk = 0; kk < 4; ++kk)
      a[kk] = *(const short8*)&z3s[(stripL + r16) * 136 + kk * 32 + quad * 8];
#pragma unroll
    for (int nt = 0; nt < 2; ++nt) {
      int o0 = wn * 32 + nt * 16;
      floatx4 acc = {0.f, 0.f, 0.f, 0.f};
#pragma unroll
      for (int kk = 0; kk < 4; ++kk) {
        short8 bfr = *(const short8*)&tn[(o0 + r16) * 136 + kk * 32 + quad * 8];
        acc = MFMA16(a[kk], bfr, acc);
      }
      float bb = bil_b[o0 + r16];
#pragma unroll
      for (int r = 0; r < 4; ++r) {
        int pxl = stripL + quad * 4 + r;
        z2s[pxl * 132 + o0 + r16] = acc[r] + bb + xres[nt][r];
      }
    }
  }
  __syncthreads();
  // ---------- LN2 -> z3s bf16 ----------
  {
    int px = tid >> 4, cl = tid & 15;           // 32 px x 16 lanes
    float4 v0 = *(const float4*)&z2s[px * 132 + cl * 8];
    float4 v1 = *(const float4*)&z2s[px * 132 + cl * 8 + 4];
    float s = v0.x + v0.y + v0.z + v0.w + v1.x + v1.y + v1.z + v1.w;
    float sq = dot4(v0, v0) + dot4(v1, v1);
    s += __shfl_xor(s, 1);  sq += __shfl_xor(sq, 1);
    s += __shfl_xor(s, 2);  sq += __shfl_xor(sq, 2);
    s += __shfl_xor(s, 4);  sq += __shfl_xor(sq, 4);
    s += __shfl_xor(s, 8);  sq += __shfl_xor(sq, 8);
    float m = s * (1.f / 128.f);
    float var = sq * (1.f / 128.f) - m * m;
    float rr = rsqrtf(var + EPS);
    int c0 = cl * 8;
    short t8[8];
#pragma unroll
    for (int j = 0; j < 8; ++j) {
      float vv = (j < 4) ? (&v0.x)[j] : (&v1.x)[j - 4];
      t8[j] = f2bf((vv - m) * rr * g2[c0 + j] + b2ln[c0 + j]);
    }
    *(uint4*)&z3s[px * 136 + c0] = *(uint4*)t8;
  }
  __syncthreads();
  // ---------- FFN (w1/w2 B-fragments direct from global; L2-hot) ----------
  short8 a3[4];
#pragma unroll
  for (int kk = 0; kk < 4; ++kk)
    a3[kk] = *(const short8*)&z3s[(stripL + r16) * 136 + kk * 32 + quad * 8];
  floatx4 zacc[2];
  zacc[0] = (floatx4){0.f, 0.f, 0.f, 0.f};
  zacc[1] = (floatx4){0.f, 0.f, 0.f, 0.f};
  for (int fc = 0; fc < 512; fc += 128) {
#pragma unroll
    for (int nt = 0; nt < 2; ++nt) {
      int f0 = wn * 32 + nt * 16;
      floatx4 acc = {0.f, 0.f, 0.f, 0.f};
#pragma unroll
      for (int kk = 0; kk < 4; ++kk) {
        short8 bfr = *(const short8*)&w1bf[(fc + f0 + r16) * 136 + kk * 32 + quad * 8];
        acc = MFMA16(a3[kk], bfr, acc);
      }
      float bb1 = b1[fc + f0 + r16];
#pragma unroll
      for (int r = 0; r < 4; ++r) {
        float hv = acc[r] + bb1;
        float ge = 0.5f * hv * (1.f + erff(hv * 0.70710678118f));
        h1s[(stripL + quad * 4 + r) * 136 + f0 + r16] = f2bf(ge);
      }
    }
    __syncthreads();
    short8 ah[4];
#pragma unroll
    for (int kk = 0; kk < 4; ++kk)
      ah[kk] = *(const short8*)&h1s[(stripL + r16) * 136 + kk * 32 + quad * 8];
    const short* w2src = w2bf + (fc >> 7) * 17408;
#pragma unroll
    for (int nt = 0; nt < 2; ++nt) {
      int o0 = wn * 32 + nt * 16;
#pragma unroll
      for (int kk = 0; kk < 4; ++kk) {
        short8 bfr = *(const short8*)&w2src[(o0 + r16) * 136 + kk * 32 + quad * 8];
        zacc[nt] = MFMA16(ah[kk], bfr, zacc[nt]);
      }
    }
    __syncthreads();  // guard next iteration's h1s overwrite
  }
  // ---------- epilogue: direct float4 stores (4 consecutive px per lane) ----------
#pragma unroll
  for (int nt = 0; nt < 2; ++nt) {
    int o = wn * 32 + nt * 16 + r16;
    float bb = b2[o];
    float res[4];
#pragma unroll
    for (int r = 0; r < 4; ++r)
      res[r] = zacc[nt][r] + bb + z2s[(stripL + quad * 4 + r) * 132 + o];
    *(float4*)&out[(((size_t)(n * 128 + o)) * 64 + y) * 64 + half * 32 + stripL + quad * 4] =
        *(float4*)res;
  }
}

// ----------------------------------------------------------------
extern "C" void kernel_launch(void* const* d_in, const int* in_sizes, int n_in,
                              void* d_out, int out_size, void* d_ws, size_t ws_size,
                              hipStream_t stream) {
  const float* x        = (const float*)d_in[0];
  const float* qcoeff   = (const float*)d_in[1];
  const float* wq       = (const float*)d_in[2];
  const float* bq       = (const float*)d_in[3];
  const float* wk       = (const float*)d_in[4];
  const float* bk       = (const float*)d_in[5];
  const float* wv       = (const float*)d_in[6];
  const float* bv       = (const float*)d_in[7];
  const float* rel_bias = (const float*)d_in[8];
  const float* ln1_g    = (const float*)d_in[9];
  const float* ln1_b    = (const float*)d_in[10];
  const float* bil_w    = (const float*)d_in[11];
  const float* bil_b    = (const float*)d_in[12];
  const float* ln2_g    = (const float*)d_in[13];
  const float* ln2_b    = (const float*)d_in[14];
  const float* w1       = (const float*)d_in[15];
  const float* b1       = (const float*)d_in[16];
  const float* w2       = (const float*)d_in[17];
  const float* b2       = (const float*)d_in[18];
  float* out = (float*)d_out;

  float* ws = (float*)d_ws;
  float* x_nhwc = ws;                    // [N,H,W,E] fp32 (residual source)
  short* qbf = (short*)(ws + 2 * SZ);    // bf16 NHWC
  short* kbf = qbf + SZ;                 // bf16 NHWC
  short* vtb = kbf + SZ;                 // bf16 transposed [n*128+o][4096]
  short* bf     = (short*)(ws + 4 * SZ); // bf16 weights
  short* tb     = bf;                    // [4][128][136]
  short* w1bf   = bf + 4 * 17408;        // [512][136]
  short* w2bf   = w1bf + 512 * 136;      // [4][128][136]
  short* wqbf   = w2bf + 4 * 17408;      // [128][136]
  short* wkbf   = wqbf + 17408;
  short* wvbf   = wkbf + 17408;

  k_prep<<<64, 256, 0, stream>>>(w1, w2, wq, wk, wv, bil_w, qcoeff,
                                 w1bf, w2bf, wqbf, wkbf, wvbf, tb);
  k_qkvln<<<512, 512, 0, stream>>>(x, ln1_g, ln1_b, wqbf, wkbf, wvbf,
                                   bq, bk, bv, x_nhwc, qbf, kbf, vtb);
  k_at<<<512, 512, 0, stream>>>(qbf, kbf, vtb, rel_bias, tb, bil_b, x_nhwc,
                                ln2_g, ln2_b, w1bf, b1, w2bf, b2, out);
}

// Round 3
// 150.985 us; speedup vs baseline: 1.0191x; 1.0191x over previous
//
#include <hip/hip_runtime.h>
#include <cmath>

#define EPS 1e-5f
#define SZ 2097152  // N*H*W*E = 4*64*64*128

typedef __attribute__((ext_vector_type(8))) short short8;   // 8 bf16 (4 VGPRs)
typedef __attribute__((ext_vector_type(4))) float floatx4;  // MFMA C/D frag

__device__ __forceinline__ float dot4(float4 a, float4 b) {
  return fmaf(a.x, b.x, fmaf(a.y, b.y, fmaf(a.z, b.z, a.w * b.w)));
}

__device__ __forceinline__ short f2bf(float f) {
  union { float f; unsigned u; } v; v.f = f;
  unsigned r = v.u + 0x7fff + ((v.u >> 16) & 1);  // RNE
  return (short)(r >> 16);
}

#define MFMA16(a, b, c) __builtin_amdgcn_mfma_f32_16x16x32_bf16(a, b, c, 0, 0, 0)

// ---------------------------------------------------------------- K0: prep (weights fp32->bf16 padded; t = bil_w.qcoeff)
// grid 256, block 256 (t-part guarded grid-stride)
__global__ __launch_bounds__(256) void k_prep(const float* __restrict__ w1,
    const float* __restrict__ w2, const float* __restrict__ wq,
    const float* __restrict__ wk, const float* __restrict__ wv,
    const float* __restrict__ bil_w, const float* __restrict__ qcoeff,
    short* __restrict__ w1bf, short* __restrict__ w2bf,
    short* __restrict__ wqbf, short* __restrict__ wkbf, short* __restrict__ wvbf,
    short* __restrict__ tb) {
  __shared__ float qs[256];
  int tid = threadIdx.x;
  qs[tid] = qcoeff[tid];
  __syncthreads();
  int tid0 = blockIdx.x * 256 + tid;
  int stride = gridDim.x * 256;
  for (int i = tid0; i < 16384; i += stride) {
    int flat = i * 4; int f = flat >> 7, c = flat & 127;
    float4 v = *(const float4*)&w1[flat];
    short t4[4] = {f2bf(v.x), f2bf(v.y), f2bf(v.z), f2bf(v.w)};
    *(uint2*)&w1bf[f * 136 + c] = *(uint2*)t4;
  }
  for (int i = tid0; i < 16384; i += stride) {
    int flat = i * 4; int o = flat >> 9, j = flat & 511;
    int ck = j >> 7, jj = j & 127;
    float4 v = *(const float4*)&w2[flat];
    short t4[4] = {f2bf(v.x), f2bf(v.y), f2bf(v.z), f2bf(v.w)};
    *(uint2*)&w2bf[(ck * 128 + o) * 136 + jj] = *(uint2*)t4;
  }
  for (int i = tid0; i < 4096; i += stride) {
    int flat = i * 4; int o = flat >> 7, c = flat & 127;
    float4 a = *(const float4*)&wq[flat];
    float4 b = *(const float4*)&wk[flat];
    float4 cc = *(const float4*)&wv[flat];
    short ta[4] = {f2bf(a.x), f2bf(a.y), f2bf(a.z), f2bf(a.w)};
    short tb4[4] = {f2bf(b.x), f2bf(b.y), f2bf(b.z), f2bf(b.w)};
    short tc[4] = {f2bf(cc.x), f2bf(cc.y), f2bf(cc.z), f2bf(cc.w)};
    *(uint2*)&wqbf[o * 136 + c] = *(uint2*)ta;
    *(uint2*)&wkbf[o * 136 + c] = *(uint2*)tb4;
    *(uint2*)&wvbf[o * 136 + c] = *(uint2*)tc;
  }
  for (int flat = tid0; flat < 16384; flat += stride) {  // o*128 + i
    const float* wrow = bil_w + (size_t)flat * 64;
    float acc[4] = {0.f, 0.f, 0.f, 0.f};
    for (int qq = 0; qq < 64; qq += 4) {
      float4 w4 = *(const float4*)&wrow[qq];
#pragma unroll
      for (int nn = 0; nn < 4; ++nn) {
        const float* qc = &qs[nn * 64 + qq];
        acc[nn] = fmaf(w4.x, qc[0], fmaf(w4.y, qc[1], fmaf(w4.z, qc[2], fmaf(w4.w, qc[3], acc[nn]))));
      }
    }
    int o = flat >> 7, i = flat & 127;
#pragma unroll
    for (int nn = 0; nn < 4; ++nn) tb[nn * 17408 + o * 136 + i] = f2bf(acc[nn]);
  }
}

// ---------------------------------------------------------------- K1: LN1 + transpose + QKV (LDS-staged weights)
// grid 512 = (n*64+y)*2+half, block 512 = 8 waves; 32 px/block; ~61 KB LDS -> 2 blocks/CU
__global__ __launch_bounds__(512) void k_qkvln(const float* __restrict__ x,
    const float* __restrict__ g, const float* __restrict__ b,
    const short* __restrict__ wqbf, const short* __restrict__ wkbf,
    const short* __restrict__ wvbf, const float* __restrict__ bq,
    const float* __restrict__ bk, const float* __restrict__ bv,
    float* __restrict__ xnhwc, short* __restrict__ qbf,
    short* __restrict__ kbf, short* __restrict__ vtb) {
  __shared__ float tile[128 * 33];               // x NCHW tile [c][xpl]
  __shared__ float mres[32], rres[32];
  __shared__ __align__(16) short xs[32 * 136];   // A: [pxl][c] bf16
  __shared__ __align__(16) short ws[128 * 136];  // B: [o][c] bf16 (staged per matrix)
  int tid = threadIdx.x;
  int bid = blockIdx.x;
  int half = bid & 1, ny = bid >> 1;
  int n = ny >> 6, y = ny & 63;
  const float* xb = x + (size_t)n * 524288 + y * 64 + half * 32;
  for (int it = 0; it < 8; ++it) {
    int flat = it * 512 + tid;                   // c*32 + xpl
    int c = flat >> 5, xpl = flat & 31;
    tile[c * 33 + xpl] = xb[(size_t)c * 4096 + xpl];
  }
  __syncthreads();
  {
    int pxl = tid >> 4, cl = tid & 15;
    float s = 0.f, sq = 0.f;
#pragma unroll
    for (int j = 0; j < 8; ++j) {
      float v = tile[(cl * 8 + j) * 33 + pxl];
      s += v; sq += v * v;
    }
    s += __shfl_xor(s, 1);  sq += __shfl_xor(sq, 1);
    s += __shfl_xor(s, 2);  sq += __shfl_xor(sq, 2);
    s += __shfl_xor(s, 4);  sq += __shfl_xor(sq, 4);
    s += __shfl_xor(s, 8);  sq += __shfl_xor(sq, 8);
    if (cl == 0) {
      float m = s * (1.f / 128.f);
      float var = sq * (1.f / 128.f) - m * m;
      mres[pxl] = m;
      rres[pxl] = rsqrtf(var + EPS);
    }
  }
  __syncthreads();
  size_t rowbase = (size_t)ny * 8192 + half * 4096;
  for (int it = 0; it < 8; ++it) {
    int flat = it * 512 + tid;                   // pxl*128 + c
    int c = flat & 127, pxl = flat >> 7;
    float v = tile[c * 33 + pxl];
    xnhwc[rowbase + flat] = v;
    xs[pxl * 136 + c] = f2bf((v - mres[pxl]) * rres[pxl] * g[c] + b[c]);
  }
  __syncthreads();
  int w = tid >> 6, lane = tid & 63;
  int quad = lane >> 4, r16 = lane & 15;
  int wm = w & 1, wn = w >> 1;                   // wn in [0,4)
  int stripl = wm * 16;
  short8 a[4];
#pragma unroll
  for (int kk = 0; kk < 4; ++kk)
    a[kk] = *(const short8*)&xs[(stripl + r16) * 136 + kk * 32 + quad * 8];
  const short* wptr[3] = {wqbf, wkbf, wvbf};
  const float* bptr[3] = {bq, bk, bv};
  for (int m = 0; m < 3; ++m) {
    __syncthreads();   // previous matrix's ws readers done
    const short* wp = wptr[m];
    for (int i = tid; i < 2176; i += 512)
      *(short8*)&ws[i * 8] = *(const short8*)&wp[i * 8];
    __syncthreads();
    const float* bb = bptr[m];
#pragma unroll
    for (int nt = 0; nt < 2; ++nt) {
      int o0 = wn * 32 + nt * 16;
      floatx4 acc = {0.f, 0.f, 0.f, 0.f};
#pragma unroll
      for (int kk = 0; kk < 4; ++kk) {
        short8 bfr = *(const short8*)&ws[(o0 + r16) * 136 + kk * 32 + quad * 8];
        acc = MFMA16(a[kk], bfr, acc);
      }
      float bv2 = bb[o0 + r16];
      if (m < 2) {
        short* dst = (m == 0) ? qbf : kbf;
#pragma unroll
        for (int r = 0; r < 4; ++r) {
          int pxl = stripl + quad * 4 + r;
          dst[rowbase + pxl * 128 + o0 + r16] = f2bf(acc[r] + bv2);
        }
      } else {
        short t4[4] = {f2bf(acc[0] + bv2), f2bf(acc[1] + bv2),
                       f2bf(acc[2] + bv2), f2bf(acc[3] + bv2)};
        *(uint2*)&vtb[(size_t)(n * 128 + o0 + r16) * 4096 + y * 64 + half * 32 +
                      stripl + quad * 4] = *(uint2*)t4;
      }
    }
  }
}

// ---------------------------------------------------------------- K2: attention + bilinear + LN2 + FFN + NCHW out
// v3: explicit register-prefetch pipelining (K batch-preload, V double-buffer,
// tb/w1/w2 fragments prefetched one phase ahead). 512 blocks x 512 threads.
__global__ __launch_bounds__(512, 4) void k_at(const short* __restrict__ qbf,
    const short* __restrict__ kbf, const short* __restrict__ vtb,
    const float* __restrict__ rel_bias, const short* __restrict__ tb,
    const float* __restrict__ bil_b, const float* __restrict__ xnhwc,
    const float* __restrict__ g2, const float* __restrict__ b2ln,
    const short* __restrict__ w1bf, const float* __restrict__ b1,
    const short* __restrict__ w2bf, const float* __restrict__ b2,
    float* __restrict__ out) {
  // layout: [0,25600) ssfw (8 waves * 16*50 f32); [25600,43008) Abw (8 * 16*68 bf16);
  // [43008,44672) bias (8 * 52 f32); h1s overlays [0,8704) in FFN phase;
  // [44672,53376) z3s [32][136] bf16; [53376,70272) z2s [32][132] f32
  __shared__ __align__(16) char smem[70272];
  short* h1s = (short*)smem;                    // FFN phase only (attn region dead then)
  short* z3s = (short*)(smem + 44672);
  float* z2s = (float*)(smem + 53376);
  int tid = threadIdx.x;
  int bid = blockIdx.x;
  int half = bid & 1, ny = bid >> 1;
  int n = ny >> 6, y = ny & 63;
  int w16 = tid >> 6, lane = tid & 63;
  int quad = lane >> 4, r16 = lane & 15;
  size_t rowbase = (size_t)ny * 8192;
  int wm = w16 & 1, wn = w16 >> 1;              // tail-phase wave tiling
  int stripL = wm * 16;                         // local px strip [0,32)
  const short* tn = tb + (size_t)n * 17408;
  // prefetch bilinear residual (x_nhwc) into registers at kernel entry
  float xres[2][4];
#pragma unroll
  for (int nt = 0; nt < 2; ++nt)
#pragma unroll
    for (int r = 0; r < 4; ++r)
      xres[nt][r] = xnhwc[rowbase + (half * 32 + stripL + quad * 4 + r) * 128 +
                          wn * 32 + nt * 16 + r16];
  short8 tf[2][4];                              // bilinear B frags (filled late in attn phase)
  // ---------- attention phase: wave = (h, local strip) ----------
  {
    int h = w16 >> 1, swl = w16 & 1;
    int sg = half * 2 + swl;                    // global strip idx [0,4)
    int strip = sg * 16;                        // global px strip
    float* ssfw = (float*)(smem + w16 * 3200);
    short* Abw = (short*)(smem + 25600 + w16 * 2176);
    float* biasw = (float*)(smem + 43008 + w16 * 208);
    // --- batch-preload Q + all 14 K fragments (one vmcnt wait, not 14 serial) ---
    const short* qrow = qbf + (size_t)n * 524288 + (size_t)y * 8192 + h * 32;
    const short* kbp = kbf + (size_t)n * 524288 + h * 32;
    short8 qf = *(const short8*)&qrow[(strip + r16) * 128 + quad * 8];
    short8 kf[7][2];
#pragma unroll
    for (int r = 0; r < 7; ++r) {
      int yyc = min(max(y + r - 3, 0), 63);
#pragma unroll
      for (int t = 0; t < 2; ++t) {
        int gxc = min(max((sg + t) * 16 + r16 - 3, 0), 63);
        kf[r][t] = *(const short8*)&kbp[(size_t)(yyc * 64 + gxc) * 128 + quad * 8];
      }
    }
    // LDS inits overlap the loads in flight
    {
      unsigned* ad = (unsigned*)Abw;
      for (int i = lane; i < 544; i += 64) ad[i] = 0u;
    }
    if (lane < 49) biasw[lane] = rel_bias[h * 49 + lane];
    // --- QK MFMA burst ---
#pragma unroll
    for (int r = 0; r < 7; ++r) {
      bool yok = (unsigned)(y + r - 3) < 64u;
#pragma unroll
      for (int t = 0; t < 2; ++t) {
        int xxc = (sg + t) * 16 + r16;
        bool ok = yok && ((unsigned)(xxc - 3) < 64u);
        floatx4 c = MFMA16(qf, kf[r][t], ((floatx4){0.f, 0.f, 0.f, 0.f}));
#pragma unroll
        for (int rr = 0; rr < 4; ++rr) {
          int lrow = quad * 4 + rr;
          int dx = xxc - (strip + lrow);
          if ((unsigned)dx < 7u) {
            float val = ok ? c[rr] : 0.f;       // reference zero-pads K
            ssfw[lrow * 50 + r * 7 + dx] = val + biasw[r * 7 + dx];
          }
        }
      }
    }
    // --- softmax over P=49 (4 lanes per row) ---
    {
      int lrow = lane >> 2, sub = lane & 3;
      int p0 = sub * 12;
      float sv[13];
      float mx = -1e30f;
#pragma unroll
      for (int pi = 0; pi < 13; ++pi) {         // p0+pi <= 48: always in-row
        sv[pi] = ssfw[lrow * 50 + p0 + pi];
        mx = fmaxf(mx, sv[pi]);
      }
      mx = fmaxf(mx, __shfl_xor(mx, 1));
      mx = fmaxf(mx, __shfl_xor(mx, 2));
      float sum = 0.f;
#pragma unroll
      for (int pi = 0; pi < 13; ++pi) {
        float e = __expf(sv[pi] - mx);
        if (pi == 12 && sub != 3) e = 0.f;      // slot belongs to next sub
        sv[pi] = e; sum += e;
      }
      sum += __shfl_xor(sum, 1);
      sum += __shfl_xor(sum, 2);
      float inv = 1.f / sum;
#pragma unroll
      for (int pi = 0; pi < 13; ++pi)
        if (pi < 12 || sub == 3) ssfw[lrow * 50 + p0 + pi] = sv[pi] * inv;
    }
    // --- PV with double-buffered V prefetch; both kk halves always (Abw zeros make extras no-ops) ---
    floatx4 oacc[2] = {(floatx4){0.f, 0.f, 0.f, 0.f}, (floatx4){0.f, 0.f, 0.f, 0.f}};
    int lrow = lane >> 2, sub = lane & 3;
    int pxg = strip + lrow;
    const short* vbp = vtb + (size_t)(n * 128 + h * 32) * 4096;
    short8 vf[2][2][2];                         // [parity][kk][nt]
    {
      int yyc0 = min(max(y - 3, 0), 63);
#pragma unroll
      for (int kk = 0; kk < 2; ++kk)
#pragma unroll
        for (int nt = 0; nt < 2; ++nt)
          vf[0][kk][nt] = *(const short8*)&vbp[(size_t)(nt * 16 + r16) * 4096 + yyc0 * 64 + kk * 32 + quad * 8];
    }
#pragma unroll
    for (int r = 0; r < 7; ++r) {
      if (r < 6) {                              // issue next row's V while computing this one
        int yycn = min(max(y + r - 2, 0), 63);
#pragma unroll
        for (int kk = 0; kk < 2; ++kk)
#pragma unroll
          for (int nt = 0; nt < 2; ++nt)
            vf[(r + 1) & 1][kk][nt] = *(const short8*)&vbp[(size_t)(nt * 16 + r16) * 4096 + yycn * 64 + kk * 32 + quad * 8];
      }
      int c0 = pxg + sub - 3;
      if ((unsigned)c0 < 64u) Abw[lrow * 68 + c0] = f2bf(ssfw[lrow * 50 + r * 7 + sub]);
      int c1 = pxg + sub + 1;
      if (sub < 3 && (unsigned)c1 < 64u)
        Abw[lrow * 68 + c1] = f2bf(ssfw[lrow * 50 + r * 7 + sub + 4]);
      if ((unsigned)(y + r - 3) < 64u) {        // reference zero-pads V: skip invalid rows (wave-uniform)
#pragma unroll
        for (int kk = 0; kk < 2; ++kk) {
          short8 af = *(const short8*)&Abw[r16 * 68 + kk * 32 + quad * 8];
#pragma unroll
          for (int nt = 0; nt < 2; ++nt)
            oacc[nt] = MFMA16(af, vf[r & 1][kk][nt], oacc[nt]);
        }
      }
    }
    // prefetch bilinear t fragments now: latency hides under z3s writes + barrier
#pragma unroll
    for (int nt = 0; nt < 2; ++nt)
#pragma unroll
      for (int kk = 0; kk < 4; ++kk)
        tf[nt][kk] = *(const short8*)&tn[(wn * 32 + nt * 16 + r16) * 136 + kk * 32 + quad * 8];
#pragma unroll
    for (int nt = 0; nt < 2; ++nt)
#pragma unroll
      for (int rr = 0; rr < 4; ++rr) {
        int pxl = swl * 16 + quad * 4 + rr;     // local px within this block's 32
        z3s[pxl * 136 + h * 32 + nt * 16 + r16] = f2bf(oacc[nt][rr]);
      }
  }
  __syncthreads();
  // ---------- bilinear (B frags already in tf) ----------
  {
    short8 a[4];
#pragma unroll
    for (int kk = 0; kk < 4; ++kk)
      a[kk] = *(const short8*)&z3s[(stripL + r16) * 136 + kk * 32 + quad * 8];
#pragma unroll
    for (int nt = 0; nt < 2; ++nt) {
      int o0 = wn * 32 + nt * 16;
      floatx4 acc = {0.f, 0.f, 0.f, 0.f};
#pragma unroll
      for (int kk = 0; kk < 4; ++kk)
        acc = MFMA16(a[kk], tf[nt][kk], acc);
      float bb = bil_b[o0 + r16];
#pragma unroll
      for (int r = 0; r < 4; ++r) {
        int pxl = stripL + quad * 4 + r;
        z2s[pxl * 132 + o0 + r16] = acc[r] + bb + xres[nt][r];
      }
    }
  }
  __syncthreads();
  // ---------- LN2 -> z3s bf16 (w1 chunk0 prefetch issued first, lands during LN2+barrier) ----------
  short8 wA[2][4];                              // w1 frags, current chunk
#pragma unroll
  for (int nt = 0; nt < 2; ++nt)
#pragma unroll
    for (int kk = 0; kk < 4; ++kk)
      wA[nt][kk] = *(const short8*)&w1bf[(wn * 32 + nt * 16 + r16) * 136 + kk * 32 + quad * 8];
  {
    int px = tid >> 4, cl = tid & 15;           // 32 px x 16 lanes
    float4 v0 = *(const float4*)&z2s[px * 132 + cl * 8];
    float4 v1 = *(const float4*)&z2s[px * 132 + cl * 8 + 4];
    float s = v0.x + v0.y + v0.z + v0.w + v1.x + v1.y + v1.z + v1.w;
    float sq = dot4(v0, v0) + dot4(v1, v1);
    s += __shfl_xor(s, 1);  sq += __shfl_xor(sq, 1);
    s += __shfl_xor(s, 2);  sq += __shfl_xor(sq, 2);
    s += __shfl_xor(s, 4);  sq += __shfl_xor(sq, 4);
    s += __shfl_xor(s, 8);  sq += __shfl_xor(sq, 8);
    float m = s * (1.f / 128.f);
    float var = sq * (1.f / 128.f) - m * m;
    float rr = rsqrtf(var + EPS);
    int c0 = cl * 8;
    short t8[8];
#pragma unroll
    for (int j = 0; j < 8; ++j) {
      float vv = (j < 4) ? (&v0.x)[j] : (&v1.x)[j - 4];
      t8[j] = f2bf((vv - m) * rr * g2[c0 + j] + b2ln[c0 + j]);
    }
    *(uint4*)&z3s[px * 136 + c0] = *(uint4*)t8;
  }
  __syncthreads();
  // ---------- FFN: 4 chunks, wA (w1) one chunk ahead, wB (w2) issued at chunk top ----------
  floatx4 zacc[2];
  zacc[0] = (floatx4){0.f, 0.f, 0.f, 0.f};
  zacc[1] = (floatx4){0.f, 0.f, 0.f, 0.f};
  for (int fc = 0; fc < 512; fc += 128) {
    short8 wB[2][4];                            // w2 chunk frags: land during hacc MFMA + gelu
#pragma unroll
    for (int nt = 0; nt < 2; ++nt)
#pragma unroll
      for (int kk = 0; kk < 4; ++kk)
        wB[nt][kk] = *(const short8*)&w2bf[((fc >> 7) * 128 + wn * 32 + nt * 16 + r16) * 136 + kk * 32 + quad * 8];
    float bb1v[2];
    bb1v[0] = b1[fc + wn * 32 + r16];
    bb1v[1] = b1[fc + wn * 32 + 16 + r16];
    short8 a3[4];
#pragma unroll
    for (int kk = 0; kk < 4; ++kk)
      a3[kk] = *(const short8*)&z3s[(stripL + r16) * 136 + kk * 32 + quad * 8];
    floatx4 hacc[2];
#pragma unroll
    for (int nt = 0; nt < 2; ++nt) {
      hacc[nt] = (floatx4){0.f, 0.f, 0.f, 0.f};
#pragma unroll
      for (int kk = 0; kk < 4; ++kk)
        hacc[nt] = MFMA16(a3[kk], wA[nt][kk], hacc[nt]);
    }
    if (fc < 384) {                             // prefetch next w1 chunk during gelu
#pragma unroll
      for (int nt = 0; nt < 2; ++nt)
#pragma unroll
        for (int kk = 0; kk < 4; ++kk)
          wA[nt][kk] = *(const short8*)&w1bf[(fc + 128 + wn * 32 + nt * 16 + r16) * 136 + kk * 32 + quad * 8];
    }
#pragma unroll
    for (int nt = 0; nt < 2; ++nt) {
      int f0 = wn * 32 + nt * 16;
#pragma unroll
      for (int r = 0; r < 4; ++r) {
        float hv = hacc[nt][r] + bb1v[nt];
        float ge = 0.5f * hv * (1.f + erff(hv * 0.70710678118f));
        h1s[(stripL + quad * 4 + r) * 136 + f0 + r16] = f2bf(ge);
      }
    }
    __syncthreads();
    short8 ah[4];
#pragma unroll
    for (int kk = 0; kk < 4; ++kk)
      ah[kk] = *(const short8*)&h1s[(stripL + r16) * 136 + kk * 32 + quad * 8];
#pragma unroll
    for (int nt = 0; nt < 2; ++nt)
#pragma unroll
      for (int kk = 0; kk < 4; ++kk)
        zacc[nt] = MFMA16(ah[kk], wB[nt][kk], zacc[nt]);
    __syncthreads();  // guard next iteration's h1s overwrite
  }
  // ---------- epilogue: direct float4 stores (4 consecutive px per lane) ----------
#pragma unroll
  for (int nt = 0; nt < 2; ++nt) {
    int o = wn * 32 + nt * 16 + r16;
    float bb = b2[o];
    float res[4];
#pragma unroll
    for (int r = 0; r < 4; ++r)
      res[r] = zacc[nt][r] + bb + z2s[(stripL + quad * 4 + r) * 132 + o];
    *(float4*)&out[(((size_t)(n * 128 + o)) * 64 + y) * 64 + half * 32 + stripL + quad * 4] =
        *(float4*)res;
  }
}

// ----------------------------------------------------------------
extern "C" void kernel_launch(void* const* d_in, const int* in_sizes, int n_in,
                              void* d_out, int out_size, void* d_ws, size_t ws_size,
                              hipStream_t stream) {
  const float* x        = (const float*)d_in[0];
  const float* qcoeff   = (const float*)d_in[1];
  const float* wq       = (const float*)d_in[2];
  const float* bq       = (const float*)d_in[3];
  const float* wk       = (const float*)d_in[4];
  const float* bk       = (const float*)d_in[5];
  const float* wv       = (const float*)d_in[6];
  const float* bv       = (const float*)d_in[7];
  const float* rel_bias = (const float*)d_in[8];
  const float* ln1_g    = (const float*)d_in[9];
  const float* ln1_b    = (const float*)d_in[10];
  const float* bil_w    = (const float*)d_in[11];
  const float* bil_b    = (const float*)d_in[12];
  const float* ln2_g    = (const float*)d_in[13];
  const float* ln2_b    = (const float*)d_in[14];
  const float* w1       = (const float*)d_in[15];
  const float* b1       = (const float*)d_in[16];
  const float* w2       = (const float*)d_in[17];
  const float* b2       = (const float*)d_in[18];
  float* out = (float*)d_out;

  float* ws = (float*)d_ws;
  float* x_nhwc = ws;                    // [N,H,W,E] fp32 (residual source)
  short* qbf = (short*)(ws + 2 * SZ);    // bf16 NHWC
  short* kbf = qbf + SZ;                 // bf16 NHWC
  short* vtb = kbf + SZ;                 // bf16 transposed [n*128+o][4096]
  short* bf     = (short*)(ws + 4 * SZ); // bf16 weights
  short* tb     = bf;                    // [4][128][136]
  short* w1bf   = bf + 4 * 17408;        // [512][136]
  short* w2bf   = w1bf + 512 * 136;      // [4][128][136]
  short* wqbf   = w2bf + 4 * 17408;      // [128][136]
  short* wkbf   = wqbf + 17408;
  short* wvbf   = wkbf + 17408;

  k_prep<<<256, 256, 0, stream>>>(w1, w2, wq, wk, wv, bil_w, qcoeff,
                                  w1bf, w2bf, wqbf, wkbf, wvbf, tb);
  k_qkvln<<<512, 512, 0, stream>>>(x, ln1_g, ln1_b, wqbf, wkbf, wvbf,
                                   bq, bk, bv, x_nhwc, qbf, kbf, vtb);
  k_at<<<512, 512, 0, stream>>>(qbf, kbf, vtb, rel_bias, tb, bil_b, x_nhwc,
                                ln2_g, ln2_b, w1bf, b1, w2bf, b2, out);
}